// Round 5
// baseline (370.807 us; speedup 1.0000x reference)
//
#include <hip/hip_runtime.h>

typedef __bf16 bf16_t;
typedef __bf16 bf16x8 __attribute__((ext_vector_type(8)));
typedef float f32x4 __attribute__((ext_vector_type(4)));

#define GM 16384   // rows of x / out
#define GN 2048    // D_OUT
#define GK 2048    // D_IN
#define NX (GM * GK)
#define NW (GN * GK)

#define NT (GK / 64)   // 32 K-tiles

// -------- merged fp32 -> bf16 convert (8 elems/thread, nt loads) --------
__global__ __launch_bounds__(256) void cvt_all(const float* __restrict__ x,
                                               const float* __restrict__ w,
                                               bf16_t* __restrict__ xb,
                                               bf16_t* __restrict__ wb) {
    long i = ((long)blockIdx.x * 256 + threadIdx.x) * 8;
    const float* s;
    bf16_t* d;
    if (i < NX) { s = x + i; d = xb + i; }          // wave-uniform branch
    else        { s = w + (i - NX); d = wb + (i - NX); }
    f32x4 v0 = __builtin_nontemporal_load((const f32x4*)s);
    f32x4 v1 = __builtin_nontemporal_load((const f32x4*)(s + 4));
    bf16x8 o;
    o[0] = (bf16_t)v0.x; o[1] = (bf16_t)v0.y; o[2] = (bf16_t)v0.z; o[3] = (bf16_t)v0.w;
    o[4] = (bf16_t)v1.x; o[5] = (bf16_t)v1.y; o[6] = (bf16_t)v1.z; o[7] = (bf16_t)v1.w;
    *(bf16x8*)d = o;   // bf16 stays cacheable — GEMM re-reads it
}

// -------- async global->LDS, 16B per lane --------
__device__ __forceinline__ void async16(const void* g, void* l) {
    __builtin_amdgcn_global_load_lds(
        (__attribute__((address_space(1))) void*)g,
        (__attribute__((address_space(3))) void*)l,
        16, 0, 0);
}

#define MEMBAR() asm volatile("" ::: "memory")
#define BARRIER() do { MEMBAR(); __builtin_amdgcn_s_barrier(); MEMBAR(); } while (0)

// -------- GEMM: C = A * B^T * scale + 0.1*bias --------
// Round-0 structure (proven 137 µs @45% MfmaUtil): 128x128 tile, BK=64,
// 4 waves, 2 blocks/CU (cross-block slip gives read/MFMA overlap).
// One change vs round-0: remove the per-K-tile vmcnt(0)+lgkmcnt(0) drain
// that __syncthreads() forces (the documented ~20% stall of this
// structure). LDS double-buffer (64 KB/block, still 2 blocks/CU) + raw
// s_barrier + COUNTED vmcnt(8): tile kt+2's 8 global_load_lds are issued
// at the boundary, the wait proves only tile kt+1's batch (issued one
// full compute phase ~2000cy earlier >> 900cy HBM latency). Steady state
// never drains vmcnt to 0. Read-drain safety at the overwrite barrier:
// every ds_read feeds an MFMA, so compiler lgkm waits drain reads before
// any wave reaches the barrier.
// Swizzle (proven, 0 conflicts): 16B chunk (row,g) of a tile lives at
// position (row, g ^ (row&7)); staging permutes the GLOBAL fetch per
// lane (same 128B row segment), LDS destination stays linear as
// global_load_lds requires.
__global__ __launch_bounds__(256, 2) void gemm_bf16_bt(
    const bf16_t* __restrict__ A,
    const bf16_t* __restrict__ B,
    const float* __restrict__ bias,
    float* __restrict__ C) {
    __shared__ bf16_t As[2][128 * 64];   // 2 x 16 KB
    __shared__ bf16_t Bs[2][128 * 64];   // 2 x 16 KB

    const int t    = threadIdx.x;
    const int bm0  = blockIdx.y * 128;
    const int bn0  = blockIdx.x * 128;

    const int wave = t >> 6;
    const int lane = t & 63;
    const int wm   = (wave >> 1) * 64;
    const int wn   = (wave & 1) * 64;
    const int fr   = lane & 15;       // frag row (m or n) == C col
    const int quad = lane >> 4;

    // Staging: issue i covers tile rows [i*32, i*32+32). Thread t is LDS
    // chunk position p = i*256 + t -> row = i*32 + (t>>3), stored-g = t&7,
    // fetches global col-group (t&7) ^ (row&7).
    const int srow = t >> 3;                         // 0..31
    const int scol = (((t & 7) ^ (srow & 7)) * 8);   // swizzled col, elems
    const bf16_t* gA0 = A + (size_t)(bm0 + srow) * GK + scol;
    const bf16_t* gB0 = B + (size_t)(bn0 + srow) * GK + scol;

    // Frag read chunk offsets: row R has R&7 == fr&7 (wm, i*16 are mult of 8)
    const int sz  = fr & 7;
    const int ch0 = ((quad)     ^ sz) * 8;   // k-half 0: chunks 0..3
    const int ch1 = ((4 + quad) ^ sz) * 8;   // k-half 1: chunks 4..7

#define STAGE(buf, k0)                                                      \
    do {                                                                    \
        _Pragma("unroll")                                                   \
        for (int i = 0; i < 4; ++i) {                                       \
            async16(gA0 + (size_t)i * 32 * GK + (k0), &As[buf][(i * 256 + t) * 8]); \
            async16(gB0 + (size_t)i * 32 * GK + (k0), &Bs[buf][(i * 256 + t) * 8]); \
        }                                                                   \
    } while (0)

    f32x4 acc[4][4] = {};

    // ---- prologue: stage K-tiles 0 and 1; prove tile 0 only ----
    STAGE(0, 0);
    STAGE(1, 64);
    asm volatile("s_waitcnt vmcnt(8)" ::: "memory");
    __builtin_amdgcn_s_barrier();
    MEMBAR();

    for (int kt = 0; kt < NT; ++kt) {
        const int cur = kt & 1;
        const bf16_t* Ac = As[cur];
        const bf16_t* Bc = Bs[cur];

        bf16x8 af[4], bf[4];
        // ---- k-half 0 ----
#pragma unroll
        for (int i = 0; i < 4; ++i)
            af[i] = *(const bf16x8*)&Ac[(wm + i * 16 + fr) * 64 + ch0];
#pragma unroll
        for (int i = 0; i < 4; ++i)
            bf[i] = *(const bf16x8*)&Bc[(wn + i * 16 + fr) * 64 + ch0];
#pragma unroll
        for (int mi = 0; mi < 4; ++mi)
#pragma unroll
            for (int ni = 0; ni < 4; ++ni)
                acc[mi][ni] = __builtin_amdgcn_mfma_f32_16x16x32_bf16(
                    af[mi], bf[ni], acc[mi][ni], 0, 0, 0);
        // ---- k-half 1 ----
#pragma unroll
        for (int i = 0; i < 4; ++i)
            af[i] = *(const bf16x8*)&Ac[(wm + i * 16 + fr) * 64 + ch1];
#pragma unroll
        for (int i = 0; i < 4; ++i)
            bf[i] = *(const bf16x8*)&Bc[(wn + i * 16 + fr) * 64 + ch1];
#pragma unroll
        for (int mi = 0; mi < 4; ++mi)
#pragma unroll
            for (int ni = 0; ni < 4; ++ni)
                acc[mi][ni] = __builtin_amdgcn_mfma_f32_16x16x32_bf16(
                    af[mi], bf[ni], acc[mi][ni], 0, 0, 0);

        if (kt == NT - 1) break;

        BARRIER();   // all waves' reads of buf[cur] consumed (drained via MFMA deps)

        if (kt + 2 < NT) {
            STAGE(cur, (size_t)(kt + 2) * 64);   // refill dead buffer
            asm volatile("s_waitcnt vmcnt(8)" ::: "memory");  // tile kt+1 landed
        } else {
            asm volatile("s_waitcnt vmcnt(0)" ::: "memory");  // tail
        }

        BARRIER();   // buf[cur^1] (tile kt+1) visible to all waves
    }

    // Epilogue: C/D layout col=lane&15, row=quad*4+reg [m89-verified].
    // Nontemporal stores: C is single-use, keep A/B resident in L2/L3.
    const float scale = 0.022097086912079608f;  // 1/sqrt(2048)
    const int crow0 = bm0 + wm + (quad << 2);
    const int ccol0 = bn0 + wn + fr;
#pragma unroll
    for (int ni = 0; ni < 4; ++ni) {
        const int col = ccol0 + ni * 16;
        const float bv = 0.1f * bias[col];
#pragma unroll
        for (int mi = 0; mi < 4; ++mi) {
            const int row = crow0 + mi * 16;
#pragma unroll
            for (int r = 0; r < 4; ++r)
                __builtin_nontemporal_store(acc[mi][ni][r] * scale + bv,
                                            &C[(size_t)(row + r) * GN + col]);
        }
    }
}

extern "C" void kernel_launch(void* const* d_in, const int* in_sizes, int n_in,
                              void* d_out, int out_size, void* d_ws, size_t ws_size,
                              hipStream_t stream) {
    const float* x = (const float*)d_in[0];   // [16384, 2048]
    const float* w = (const float*)d_in[1];   // [2048, 2048]
    const float* b = (const float*)d_in[2];   // [1, 2048]
    float* out = (float*)d_out;               // [16384, 2048]

    bf16_t* xb = (bf16_t*)d_ws;                   // 64 MiB
    bf16_t* wb = xb + (size_t)NX;                 // + 8 MiB

    cvt_all<<<(NX + NW) / (8 * 256), 256, 0, stream>>>(x, w, xb, wb);

    dim3 grid(GN / 128, GM / 128);   // (16, 128) = 2048 blocks
    gemm_bf16_bt<<<grid, 256, 0, stream>>>(xb, wb, b, out);
}